// Round 6
// baseline (235.694 us; speedup 1.0000x reference)
//
#include <hip/hip_runtime.h>

#define NTOK 32768   // 8*64*64 tokens
#define CIN 192
#define C3 576
#define HEADS 8
#define HD 24

typedef __attribute__((ext_vector_type(8))) short bf16x8;
typedef __attribute__((ext_vector_type(16))) float f32x16;
typedef __attribute__((ext_vector_type(4))) unsigned int u32x4;

__device__ __forceinline__ float bf2f(unsigned int u) {
  union { unsigned int i; float f; } x; x.i = u << 16; return x.f;
}
__device__ __forceinline__ unsigned short f2bf(float f) {
  union { float f; unsigned int i; } x; x.f = f;
  unsigned int r = x.i + 0x7fffu + ((x.i >> 16) & 1u);
  return (unsigned short)(r >> 16);
}

// ---------------------------------------------------------------------------
// MFMA GEMM: Y[o,n] = bias[o] + sum_{c<192} W[o,c] * X[c,n]
// block 256 = 4 waves; tile 64(o) x 64(n); full K=192 staged once.
// Fragment-linear LDS: 16B chunk index = kk*128 + hi*64 + (o|n).
//   - wave's MFMA operand read = 64 consecutive chunks -> conflict-free
//   - staging: one o/n per thread, c-run of 48 -> per-(kk,hi) b128 writes are
//     64 consecutive chunks -> conflict-free
// 1D grid, XCD-chunked swizzle (o fastest within an XCD's n-range).
// ---------------------------------------------------------------------------
template<int XBF, int OUTF32>
__global__ __launch_bounds__(256) void k_gemm_mfma(
    const void* __restrict__ Xv, const float* __restrict__ W,
    const float* __restrict__ bias, void* __restrict__ Yv, int ot)
{
  __shared__ __align__(16) unsigned short Wf[12 * 128 * 8];   // 24 KB
  __shared__ __align__(16) unsigned short Xf[12 * 128 * 8];   // 24 KB
  const int tid = threadIdx.x;
  const int bid = blockIdx.x;
  const int loc = bid >> 3;
  const int n0 = ((bid & 7) * 64 + loc / ot) * 64;
  const int o0 = (loc % ot) * 64;

  { // stage W: thread owns row o, c-run cq*48..+47 (fp32 -> bf16)
    const int o = tid & 63;
    const int cq = tid >> 6;
    const float* wrow = &W[(size_t)(o0 + o) * CIN + cq * 48];
    unsigned short tmp[48];
#pragma unroll
    for (int j = 0; j < 12; ++j) {
      float4 v = *(const float4*)&wrow[j * 4];
      tmp[j * 4]     = f2bf(v.x);
      tmp[j * 4 + 1] = f2bf(v.y);
      tmp[j * 4 + 2] = f2bf(v.z);
      tmp[j * 4 + 3] = f2bf(v.w);
    }
#pragma unroll
    for (int kq = 0; kq < 3; ++kq)
#pragma unroll
      for (int hi = 0; hi < 2; ++hi) {
        const int kk = cq * 3 + kq;
        *(bf16x8*)&Wf[(kk * 128 + hi * 64 + o) * 8] =
            *(const bf16x8*)&tmp[kq * 16 + hi * 8];
      }
  }
  { // stage X: thread owns col n, c-run cq*48..+47 (coalesced across lanes)
    const int n = tid & 63;
    const int cq = tid >> 6;
    unsigned short tmp[48];
    if (XBF) {
      const unsigned short* X =
          (const unsigned short*)Xv + (size_t)(cq * 48) * NTOK + n0 + n;
#pragma unroll
      for (int j = 0; j < 48; ++j) tmp[j] = X[(size_t)j * NTOK];
    } else {
      const float* X = (const float*)Xv + (size_t)(cq * 48) * NTOK + n0 + n;
#pragma unroll
      for (int j = 0; j < 48; ++j) tmp[j] = f2bf(X[(size_t)j * NTOK]);
    }
#pragma unroll
    for (int kq = 0; kq < 3; ++kq)
#pragma unroll
      for (int hi = 0; hi < 2; ++hi) {
        const int kk = cq * 3 + kq;
        *(bf16x8*)&Xf[(kk * 128 + hi * 64 + n) * 8] =
            *(const bf16x8*)&tmp[kq * 16 + hi * 8];
      }
  }
  __syncthreads();

  const int lane = tid & 63;
  const int wv = tid >> 6;
  const int o_w = (wv >> 1) * 32;
  const int n_w = (wv & 1) * 32;
  const int r32 = lane & 31;
  const int hi = lane >> 5;

  f32x16 acc;
#pragma unroll
  for (int i = 0; i < 16; ++i) acc[i] = 0.f;

  const unsigned short* wp = &Wf[(hi * 64 + o_w + r32) * 8];
  const unsigned short* xp = &Xf[(hi * 64 + n_w + r32) * 8];
#pragma unroll
  for (int kk = 0; kk < 12; ++kk) {
    bf16x8 a = *(const bf16x8*)(wp + kk * 1024);
    bf16x8 b = *(const bf16x8*)(xp + kk * 1024);
    acc = __builtin_amdgcn_mfma_f32_32x32x16_bf16(a, b, acc, 0, 0, 0);
  }
  __syncthreads();

  if (OUTF32) {
    float (*Yl)[68] = (float(*)[68])&Wf[0];   // 17408 B <= 24576 B
#pragma unroll
    for (int r = 0; r < 16; ++r) {
      const int row = o_w + (r & 3) + 8 * (r >> 2) + 4 * hi;
      Yl[row][n_w + r32] = acc[r] + bias[o0 + row];
    }
    __syncthreads();
    float* Y = (float*)Yv;
    const int row = tid >> 2, seg = (tid & 3) * 16;
#pragma unroll
    for (int v = 0; v < 4; ++v) {
      float4 val = *(const float4*)&Yl[row][seg + v * 4];
      *(float4*)&Y[(size_t)(o0 + row) * NTOK + n0 + seg + v * 4] = val;
    }
  } else {
    unsigned short (*Yl)[72] = (unsigned short(*)[72])&Wf[0];  // 9216 B
#pragma unroll
    for (int r = 0; r < 16; ++r) {
      const int row = o_w + (r & 3) + 8 * (r >> 2) + 4 * hi;
      Yl[row][n_w + r32] = f2bf(acc[r] + bias[o0 + row]);
    }
    __syncthreads();
    unsigned short* Y = (unsigned short*)Yv;
    const int row = tid >> 2, seg = (tid & 3) * 16;
#pragma unroll
    for (int v = 0; v < 2; ++v) {
      bf16x8 val = *(const bf16x8*)&Yl[row][seg + v * 8];
      *(bf16x8*)&Y[(size_t)(o0 + row) * NTOK + n0 + seg + v * 8] = val;
    }
  }
}

// ---------------------------------------------------------------------------
// K2: depthwise 3x3x3, pad 1, bf16 in/out, fp32 math.
// Register sliding-window; bf16 LDS (21.9 KB), 16B-aligned dwordx4 staging.
// ---------------------------------------------------------------------------
__global__ __launch_bounds__(256, 4) void k_dwconv(
    const unsigned short* __restrict__ in,   // [CH_chunk][8][64][64] bf16
    const float* __restrict__ wdw,           // [576][27]
    const float* __restrict__ bdw,           // [576]
    unsigned short* __restrict__ out,        // [576][8][64][64] bf16
    int c_start)
{
  __shared__ __align__(16) unsigned short s[8][18][76];
  const int tid = threadIdx.x;
  const int chl = blockIdx.y;
  const int ch = c_start + chl;
  const int h0 = blockIdx.x * 16;
  const unsigned short* inch = in + (size_t)chl * NTOK;

  for (int r = tid; r < 144; r += 256) {
    const int t = r / 18, rr = r % 18;
    s[t][rr][7] = 0;
    s[t][rr][72] = 0;
  }
  for (int idx = tid; idx < 144 * 8; idx += 256) {
    const int row = idx >> 3, seg = idx & 7;
    const int t = row / 18, rr = row % 18;
    const int h = h0 + rr - 1;
    u32x4 v = {0u, 0u, 0u, 0u};
    if (h >= 0 && h < 64)
      v = *(const u32x4*)&inch[t * 4096 + h * 64 + seg * 8];
    *(u32x4*)&s[t][rr][8 + seg * 8] = v;
  }
  float wr[27];
#pragma unroll
  for (int i = 0; i < 27; ++i) wr[i] = wdw[ch * 27 + i];
  const float bias = bdw[ch];
  __syncthreads();

  const int wloc = tid & 63;
  const int hl0 = (tid >> 6) * 4;
  float acc[8][4];
#pragma unroll
  for (int t = 0; t < 8; ++t)
#pragma unroll
    for (int i = 0; i < 4; ++i) acc[t][i] = 0.f;

#pragma unroll
  for (int tt = 0; tt < 8; ++tt) {
    float v[6][3];
#pragma unroll
    for (int r = 0; r < 6; ++r)
#pragma unroll
      for (int c = 0; c < 3; ++c)
        v[r][c] = bf2f(s[tt][hl0 + r][7 + wloc + c]);
#pragma unroll
    for (int p = 0; p < 3; ++p) {
      const int t = tt + 1 - p;
      if (t < 0 || t > 7) continue;
#pragma unroll
      for (int hi = 0; hi < 4; ++hi) {
        float a = 0.f;
#pragma unroll
        for (int dh = 0; dh < 3; ++dh)
#pragma unroll
          for (int dw = 0; dw < 3; ++dw)
            a += wr[p * 9 + dh * 3 + dw] * v[hi + dh][dw];
        acc[t][hi] += a;
      }
    }
  }

  unsigned short* outch = out + (size_t)ch * NTOK;
#pragma unroll
  for (int t = 0; t < 8; ++t)
#pragma unroll
    for (int hi = 0; hi < 4; ++hi)
      outch[t * 4096 + (h0 + hl0 + hi) * 64 + wloc] = f2bf(acc[t][hi] + bias);
}

// ---------------------------------------------------------------------------
// K3: Gram via MFMA, fragments loaded DIRECTLY from global (no LDS staging).
// ---------------------------------------------------------------------------
__global__ __launch_bounds__(256) void k_gram(
    const unsigned short* __restrict__ post,
    float* __restrict__ Sb, float* __restrict__ nqb, float* __restrict__ nkb)
{
  const int tid = threadIdx.x;
  const int h = blockIdx.y;
  const int lane = tid & 63;
  const int wv = tid >> 6;
  const int c = lane & 31;
  const int off = (lane >> 5) * 8;
  const unsigned short* q = post + (size_t)(h * HD + c) * NTOK;
  const unsigned short* k = post + (size_t)(192 + h * HD + c) * NTOK;

  __shared__ float Sl[24][25];
  __shared__ float nl[48];
  for (int i = tid; i < 600; i += 256) ((float*)Sl)[i] = 0.f;
  if (tid < 48) nl[tid] = 0.f;
  __syncthreads();

  f32x16 acc;
#pragma unroll
  for (int i = 0; i < 16; ++i) acc[i] = 0.f;
  float sqq = 0.f, sqk = 0.f;

  const int base = blockIdx.x * 1024 + wv * 256 + off;
#pragma unroll
  for (int i = 0; i < 16; ++i) {
    const int n = base + i * 16;
    bf16x8 a = *(const bf16x8*)&q[n];
    bf16x8 b = *(const bf16x8*)&k[n];
#pragma unroll
    for (int e = 0; e < 8; ++e) {
      float fa = bf2f((unsigned short)a[e]);
      float fb = bf2f((unsigned short)b[e]);
      sqq += fa * fa;
      sqk += fb * fb;
    }
    acc = __builtin_amdgcn_mfma_f32_32x32x16_bf16(a, b, acc, 0, 0, 0);
  }

  sqq += __shfl_down(sqq, 32, 64);
  sqk += __shfl_down(sqk, 32, 64);
  if (lane < 32 && c < 24) {
    atomicAdd(&nl[c], sqq);
    atomicAdd(&nl[24 + c], sqk);
  }
  if (c < 24) {
#pragma unroll
    for (int r = 0; r < 16; ++r) {
      const int row = (r & 3) + 8 * (r >> 2) + 4 * (lane >> 5);
      if (row < 24) atomicAdd(&Sl[row][c], acc[r]);
    }
  }
  __syncthreads();
  for (int i = tid; i < 576; i += 256)
    atomicAdd(&Sb[h * 576 + i], Sl[i / 24][i % 24]);
  if (tid < 24) atomicAdd(&nqb[h * 24 + tid], nl[tid]);
  else if (tid < 48) atomicAdd(&nkb[h * 24 + tid - 24], nl[tid]);
}

// ---------------------------------------------------------------------------
// K4: attn = softmax(S*temp/(|q||k|)); Wcomb = projW @ attn (per head)
// ---------------------------------------------------------------------------
__global__ __launch_bounds__(256) void k_attn_wcomb(
    const float* __restrict__ Sb, const float* __restrict__ nqb,
    const float* __restrict__ nkb, const float* __restrict__ temp,
    const float* __restrict__ projw, float* __restrict__ wcomb)
{
  const int h = blockIdx.x;
  const int tid = threadIdx.x;
  __shared__ float attn[24][25];
  __shared__ float nqs[24], nks[24];
  if (tid < 24) nqs[tid] = fmaxf(sqrtf(nqb[h * 24 + tid]), 1e-12f);
  else if (tid < 48) nks[tid - 24] = fmaxf(sqrtf(nkb[h * 24 + tid - 24]), 1e-12f);
  __syncthreads();
  if (tid < 24) {
    const int c = tid;
    const float tmp = temp[h];
    float row[24];
    float m = -1e30f;
#pragma unroll
    for (int d = 0; d < 24; ++d) {
      float v = Sb[h * 576 + c * 24 + d] / (nqs[c] * nks[d]) * tmp;
      row[d] = v;
      m = fmaxf(m, v);
    }
    float ssum = 0.f;
#pragma unroll
    for (int d = 0; d < 24; ++d) { float e = __expf(row[d] - m); row[d] = e; ssum += e; }
    const float inv = 1.f / ssum;
#pragma unroll
    for (int d = 0; d < 24; ++d) attn[c][d] = row[d] * inv;
  }
  __syncthreads();
  for (int e = tid; e < 192 * 24; e += 256) {
    int o = e / 24, d = e % 24;
    float a = 0.f;
#pragma unroll
    for (int c = 0; c < 24; ++c) a += projw[o * 192 + h * 24 + c] * attn[c][d];
    wcomb[o * 192 + h * 24 + d] = a;
  }
}

// ---------------------------------------------------------------------------
extern "C" void kernel_launch(void* const* d_in, const int* in_sizes, int n_in,
                              void* d_out, int out_size, void* d_ws, size_t ws_size,
                              hipStream_t stream) {
  const float* x      = (const float*)d_in[0];
  const float* qkv_w  = (const float*)d_in[1];
  const float* qkv_b  = (const float*)d_in[2];
  const float* dw_w   = (const float*)d_in[3];
  const float* dw_b   = (const float*)d_in[4];
  const float* temp   = (const float*)d_in[5];
  const float* proj_w = (const float*)d_in[6];
  const float* proj_b = (const float*)d_in[7];
  float* out = (float*)d_out;

  char* ws = (char*)d_ws;
  size_t off = 0;
  unsigned short* post = (unsigned short*)(ws + off);
  off += (size_t)C3 * NTOK * sizeof(unsigned short);           // 37.75 MB
  float* Sb0  = (float*)(ws + off);
  float* nqb0 = Sb0 + 2 * HEADS * HD * HD;
  float* nkb0 = nqb0 + 2 * HEADS * HD;
  size_t stotal = (size_t)(2 * HEADS * HD * HD + 4 * HEADS * HD) * sizeof(float);
  off += stotal;
  float* wcomb = (float*)(ws + off); off += (size_t)CIN * CIN * sizeof(float);
  off = (off + 255) & ~(size_t)255;
  unsigned short* pre = (unsigned short*)(ws + off);

  size_t remain = (ws_size > off) ? ws_size - off : 0;
  int CH = (int)(remain / ((size_t)NTOK * sizeof(unsigned short)));
  if (CH > C3) CH = C3;
  CH = (CH / 64) * 64;
  if (CH < 64) CH = 64;

  hipMemsetAsync(Sb0, 0, stotal, stream);

  for (int b = 0; b < 2; ++b) {
    const float* xb = x + (size_t)b * CIN * NTOK;
    for (int cs = 0; cs < C3; cs += CH) {
      int cc = C3 - cs; if (cc > CH) cc = CH;
      int ot = cc / 64;
      dim3 g1((NTOK / 64) * ot);
      k_gemm_mfma<0, 0><<<g1, 256, 0, stream>>>(xb, qkv_w + (size_t)cs * CIN,
                                                qkv_b + cs, pre, ot);
      dim3 g2(4, cc);
      k_dwconv<<<g2, 256, 0, stream>>>(pre, dw_w, dw_b, post, cs);
    }
    float* Sb  = Sb0 + (size_t)b * HEADS * HD * HD;
    float* nqb = nqb0 + (size_t)b * HEADS * HD;
    float* nkb = nkb0 + (size_t)b * HEADS * HD;
    dim3 g3(32, HEADS);
    k_gram<<<g3, 256, 0, stream>>>(post, Sb, nqb, nkb);
    k_attn_wcomb<<<HEADS, 256, 0, stream>>>(Sb, nqb, nkb, temp, proj_w, wcomb);
    dim3 g5((NTOK / 64) * 3);
    k_gemm_mfma<1, 1><<<g5, 256, 0, stream>>>(post + (size_t)384 * NTOK, wcomb,
                                              proj_b, out + (size_t)b * CIN * NTOK, 3);
  }
}

// Round 7
// 232.280 us; speedup vs baseline: 1.0147x; 1.0147x over previous
//
#include <hip/hip_runtime.h>

#define NTOK 32768   // 8*64*64 tokens
#define CIN 192
#define C3 576
#define HEADS 8
#define HD 24

typedef __attribute__((ext_vector_type(8))) short bf16x8;
typedef __attribute__((ext_vector_type(16))) float f32x16;
typedef __attribute__((ext_vector_type(4))) unsigned int u32x4;

__device__ __forceinline__ float bf2f(unsigned int u) {
  union { unsigned int i; float f; } x; x.i = u << 16; return x.f;
}
__device__ __forceinline__ unsigned short f2bf(float f) {
  union { float f; unsigned int i; } x; x.f = f;
  unsigned int r = x.i + 0x7fffu + ((x.i >> 16) & 1u);
  return (unsigned short)(r >> 16);
}

// ---------------------------------------------------------------------------
// k_wfrag: fp32 W[O][192] -> bf16 MFMA-A-fragment-linear table.
// chunk g = ((otile*12 + kk)*2 + hi)*64 + olane  holds W[otile*64+olane][kk*16+hi*8 .. +7]
// A-frag load in GEMM = one contiguous 16B read per lane, coalesced per wave.
// ---------------------------------------------------------------------------
__global__ __launch_bounds__(256) void k_wfrag(const float* __restrict__ W,
                                               unsigned short* __restrict__ Wf,
                                               int nchunk) {
  const int g = blockIdx.x * 256 + threadIdx.x;
  if (g >= nchunk) return;
  const int ol = g & 63, hi = (g >> 6) & 1, kk = (g >> 7) % 12, ot = g / 1536;
  const float* src = W + (size_t)(ot * 64 + ol) * CIN + kk * 16 + hi * 8;
  bf16x8 p;
#pragma unroll
  for (int e = 0; e < 8; ++e) p[e] = (short)f2bf(src[e]);
  *(bf16x8*)&Wf[(size_t)g * 8] = p;
}

// ---------------------------------------------------------------------------
// k_gemm_rr: Y[o,n] = bias[o] + sum_c W[o,c]*X[c,n], K=192 fully unrolled.
// Block = one 64-n tile; X staged to LDS once, repacked into 12 reg B-frags;
// loop over all `ot` 64-o tiles streaming pre-packed A-frags from global (L2).
// 4 waves: o_w = (wv>>1)*32, n_w = (wv&1)*32. LDS reused for epilogue repack.
// ---------------------------------------------------------------------------
template<int XBF, int OUTF32>
__global__ __launch_bounds__(256) void k_gemm_rr(
    const void* __restrict__ Xv, const unsigned short* __restrict__ Wf,
    const float* __restrict__ bias, void* __restrict__ Yv, int ot)
{
  __shared__ __align__(16) char lds[26112];
  unsigned short (*Xl)[68] = (unsigned short(*)[68])lds;   // [192][68] bf16
  const int tid = threadIdx.x;
  const int n0 = blockIdx.x * 64;

  // ---- stage X -> Xl[c][n] (vectorized, coalesced)
  if (XBF) {
    const unsigned short* X = (const unsigned short*)Xv;
#pragma unroll
    for (int i = 0; i < 12; ++i) {
      const int g = tid + i * 256;          // 0..3071
      const int c = g >> 4, nq = (g & 15) * 4;
      *(unsigned long long*)&Xl[c][nq] =
          *(const unsigned long long*)&X[(size_t)c * NTOK + n0 + nq];
    }
  } else {
    const float* X = (const float*)Xv;
#pragma unroll
    for (int i = 0; i < 12; ++i) {
      const int g = tid + i * 256;
      const int c = g >> 4, nq = (g & 15) * 4;
      float4 v = *(const float4*)&X[(size_t)c * NTOK + n0 + nq];
      unsigned short p[4] = {f2bf(v.x), f2bf(v.y), f2bf(v.z), f2bf(v.w)};
      *(unsigned long long*)&Xl[c][nq] = *(unsigned long long*)p;
    }
  }
  __syncthreads();

  const int lane = tid & 63;
  const int wv = tid >> 6;
  const int o_w = (wv >> 1) * 32;
  const int n_w = (wv & 1) * 32;
  const int j = lane & 31;
  const int hi = lane >> 5;

  // ---- repack B-frags to registers (conflict-free: hi shifts 16 banks)
  bf16x8 bfr[12];
#pragma unroll
  for (int kk = 0; kk < 12; ++kk)
#pragma unroll
    for (int e = 0; e < 8; ++e)
      bfr[kk][e] = (short)Xl[kk * 16 + hi * 8 + e][n_w + j];
  __syncthreads();   // all waves done with Xl -> reuse lds for epilogue

  for (int it = 0; it < ot; ++it) {
    f32x16 acc0, acc1;
#pragma unroll
    for (int i = 0; i < 16; ++i) { acc0[i] = 0.f; acc1[i] = 0.f; }
    const unsigned short* wp =
        Wf + ((size_t)it * 1536 + hi * 64 + o_w + j) * 8;
#pragma unroll
    for (int kp = 0; kp < 6; ++kp) {
      bf16x8 a0 = *(const bf16x8*)(wp + (2 * kp) * 1024);
      bf16x8 a1 = *(const bf16x8*)(wp + (2 * kp + 1) * 1024);
      acc0 = __builtin_amdgcn_mfma_f32_32x32x16_bf16(a0, bfr[2 * kp], acc0, 0, 0, 0);
      acc1 = __builtin_amdgcn_mfma_f32_32x32x16_bf16(a1, bfr[2 * kp + 1], acc1, 0, 0, 0);
    }
    const int o0 = it * 64;
    __syncthreads();   // protect previous iteration's readout
    if (OUTF32) {
      float (*Yl)[68] = (float(*)[68])lds;   // 17408 B
#pragma unroll
      for (int r = 0; r < 16; ++r) {
        const int row = o_w + (r & 3) + 8 * (r >> 2) + 4 * hi;
        Yl[row][n_w + j] = acc0[r] + acc1[r] + bias[o0 + row];
      }
      __syncthreads();
      float* Y = (float*)Yv;
      const int row = tid >> 2, seg = (tid & 3) * 16;
#pragma unroll
      for (int v = 0; v < 4; ++v) {
        float4 val = *(const float4*)&Yl[row][seg + v * 4];
        *(float4*)&Y[(size_t)(o0 + row) * NTOK + n0 + seg + v * 4] = val;
      }
    } else {
      unsigned short (*Yl)[72] = (unsigned short(*)[72])lds;  // 9216 B
#pragma unroll
      for (int r = 0; r < 16; ++r) {
        const int row = o_w + (r & 3) + 8 * (r >> 2) + 4 * hi;
        Yl[row][n_w + j] = f2bf(acc0[r] + acc1[r] + bias[o0 + row]);
      }
      __syncthreads();
      unsigned short* Y = (unsigned short*)Yv;
      const int row = tid >> 2, seg = (tid & 3) * 16;
#pragma unroll
      for (int v = 0; v < 2; ++v) {
        bf16x8 val = *(const bf16x8*)&Yl[row][seg + v * 8];
        *(bf16x8*)&Y[(size_t)(o0 + row) * NTOK + n0 + seg + v * 8] = val;
      }
    }
  }
}

// ---------------------------------------------------------------------------
// K2: depthwise 3x3x3, pad 1, bf16 in/out, fp32 math. (unchanged)
// ---------------------------------------------------------------------------
__global__ __launch_bounds__(256, 4) void k_dwconv(
    const unsigned short* __restrict__ in,   // [576][8][64][64] bf16
    const float* __restrict__ wdw,           // [576][27]
    const float* __restrict__ bdw,           // [576]
    unsigned short* __restrict__ out)        // [576][8][64][64] bf16
{
  __shared__ __align__(16) unsigned short s[8][18][76];
  const int tid = threadIdx.x;
  const int ch = blockIdx.y;
  const int h0 = blockIdx.x * 16;
  const unsigned short* inch = in + (size_t)ch * NTOK;

  for (int r = tid; r < 144; r += 256) {
    const int t = r / 18, rr = r % 18;
    s[t][rr][7] = 0;
    s[t][rr][72] = 0;
  }
  for (int idx = tid; idx < 144 * 8; idx += 256) {
    const int row = idx >> 3, seg = idx & 7;
    const int t = row / 18, rr = row % 18;
    const int h = h0 + rr - 1;
    u32x4 v = {0u, 0u, 0u, 0u};
    if (h >= 0 && h < 64)
      v = *(const u32x4*)&inch[t * 4096 + h * 64 + seg * 8];
    *(u32x4*)&s[t][rr][8 + seg * 8] = v;
  }
  float wr[27];
#pragma unroll
  for (int i = 0; i < 27; ++i) wr[i] = wdw[ch * 27 + i];
  const float bias = bdw[ch];
  __syncthreads();

  const int wloc = tid & 63;
  const int hl0 = (tid >> 6) * 4;
  float acc[8][4];
#pragma unroll
  for (int t = 0; t < 8; ++t)
#pragma unroll
    for (int i = 0; i < 4; ++i) acc[t][i] = 0.f;

#pragma unroll
  for (int tt = 0; tt < 8; ++tt) {
    float v[6][3];
#pragma unroll
    for (int r = 0; r < 6; ++r)
#pragma unroll
      for (int c = 0; c < 3; ++c)
        v[r][c] = bf2f(s[tt][hl0 + r][7 + wloc + c]);
#pragma unroll
    for (int p = 0; p < 3; ++p) {
      const int t = tt + 1 - p;
      if (t < 0 || t > 7) continue;
#pragma unroll
      for (int hi = 0; hi < 4; ++hi) {
        float a = 0.f;
#pragma unroll
        for (int dh = 0; dh < 3; ++dh)
#pragma unroll
          for (int dw = 0; dw < 3; ++dw)
            a += wr[p * 9 + dh * 3 + dw] * v[hi + dh][dw];
        acc[t][hi] += a;
      }
    }
  }

  unsigned short* outch = out + (size_t)ch * NTOK;
#pragma unroll
  for (int t = 0; t < 8; ++t)
#pragma unroll
    for (int hi = 0; hi < 4; ++hi)
      outch[t * 4096 + (h0 + hl0 + hi) * 64 + wloc] = f2bf(acc[t][hi] + bias);
}

// ---------------------------------------------------------------------------
// K3: Gram via MFMA, fragments loaded DIRECTLY from global. (unchanged)
// ---------------------------------------------------------------------------
__global__ __launch_bounds__(256) void k_gram(
    const unsigned short* __restrict__ post,
    float* __restrict__ Sb, float* __restrict__ nqb, float* __restrict__ nkb)
{
  const int tid = threadIdx.x;
  const int h = blockIdx.y;
  const int lane = tid & 63;
  const int wv = tid >> 6;
  const int c = lane & 31;
  const int off = (lane >> 5) * 8;
  const unsigned short* q = post + (size_t)(h * HD + c) * NTOK;
  const unsigned short* k = post + (size_t)(192 + h * HD + c) * NTOK;

  __shared__ float Sl[24][25];
  __shared__ float nl[48];
  for (int i = tid; i < 600; i += 256) ((float*)Sl)[i] = 0.f;
  if (tid < 48) nl[tid] = 0.f;
  __syncthreads();

  f32x16 acc;
#pragma unroll
  for (int i = 0; i < 16; ++i) acc[i] = 0.f;
  float sqq = 0.f, sqk = 0.f;

  const int base = blockIdx.x * 1024 + wv * 256 + off;
#pragma unroll
  for (int i = 0; i < 16; ++i) {
    const int n = base + i * 16;
    bf16x8 a = *(const bf16x8*)&q[n];
    bf16x8 b = *(const bf16x8*)&k[n];
#pragma unroll
    for (int e = 0; e < 8; ++e) {
      float fa = bf2f((unsigned short)a[e]);
      float fb = bf2f((unsigned short)b[e]);
      sqq += fa * fa;
      sqk += fb * fb;
    }
    acc = __builtin_amdgcn_mfma_f32_32x32x16_bf16(a, b, acc, 0, 0, 0);
  }

  sqq += __shfl_down(sqq, 32, 64);
  sqk += __shfl_down(sqk, 32, 64);
  if (lane < 32 && c < 24) {
    atomicAdd(&nl[c], sqq);
    atomicAdd(&nl[24 + c], sqk);
  }
  if (c < 24) {
#pragma unroll
    for (int r = 0; r < 16; ++r) {
      const int row = (r & 3) + 8 * (r >> 2) + 4 * (lane >> 5);
      if (row < 24) atomicAdd(&Sl[row][c], acc[r]);
    }
  }
  __syncthreads();
  for (int i = tid; i < 576; i += 256)
    atomicAdd(&Sb[h * 576 + i], Sl[i / 24][i % 24]);
  if (tid < 24) atomicAdd(&nqb[h * 24 + tid], nl[tid]);
  else if (tid < 48) atomicAdd(&nkb[h * 24 + tid - 24], nl[tid]);
}

// ---------------------------------------------------------------------------
// K4: attn = softmax(S*temp/(|q||k|)); Wcomb = projW @ attn (per head)
// ---------------------------------------------------------------------------
__global__ __launch_bounds__(256) void k_attn_wcomb(
    const float* __restrict__ Sb, const float* __restrict__ nqb,
    const float* __restrict__ nkb, const float* __restrict__ temp,
    const float* __restrict__ projw, float* __restrict__ wcomb)
{
  const int h = blockIdx.x;
  const int tid = threadIdx.x;
  __shared__ float attn[24][25];
  __shared__ float nqs[24], nks[24];
  if (tid < 24) nqs[tid] = fmaxf(sqrtf(nqb[h * 24 + tid]), 1e-12f);
  else if (tid < 48) nks[tid - 24] = fmaxf(sqrtf(nkb[h * 24 + tid - 24]), 1e-12f);
  __syncthreads();
  if (tid < 24) {
    const int c = tid;
    const float tmp = temp[h];
    float row[24];
    float m = -1e30f;
#pragma unroll
    for (int d = 0; d < 24; ++d) {
      float v = Sb[h * 576 + c * 24 + d] / (nqs[c] * nks[d]) * tmp;
      row[d] = v;
      m = fmaxf(m, v);
    }
    float ssum = 0.f;
#pragma unroll
    for (int d = 0; d < 24; ++d) { float e = __expf(row[d] - m); row[d] = e; ssum += e; }
    const float inv = 1.f / ssum;
#pragma unroll
    for (int d = 0; d < 24; ++d) attn[c][d] = row[d] * inv;
  }
  __syncthreads();
  for (int e = tid; e < 192 * 24; e += 256) {
    int o = e / 24, d = e % 24;
    float a = 0.f;
#pragma unroll
    for (int c = 0; c < 24; ++c) a += projw[o * 192 + h * 24 + c] * attn[c][d];
    wcomb[o * 192 + h * 24 + d] = a;
  }
}

// ---------------------------------------------------------------------------
extern "C" void kernel_launch(void* const* d_in, const int* in_sizes, int n_in,
                              void* d_out, int out_size, void* d_ws, size_t ws_size,
                              hipStream_t stream) {
  const float* x      = (const float*)d_in[0];
  const float* qkv_w  = (const float*)d_in[1];
  const float* qkv_b  = (const float*)d_in[2];
  const float* dw_w   = (const float*)d_in[3];
  const float* dw_b   = (const float*)d_in[4];
  const float* temp   = (const float*)d_in[5];
  const float* proj_w = (const float*)d_in[6];
  const float* proj_b = (const float*)d_in[7];
  float* out = (float*)d_out;

  char* ws = (char*)d_ws;
  size_t off = 0;
  unsigned short* post = (unsigned short*)(ws + off);
  off += (size_t)C3 * NTOK * sizeof(unsigned short);           // 37.75 MB
  unsigned short* pre = (unsigned short*)(ws + off);
  off += (size_t)C3 * NTOK * sizeof(unsigned short);           // 37.75 MB
  float* Sb0  = (float*)(ws + off);
  float* nqb0 = Sb0 + 2 * HEADS * HD * HD;
  float* nkb0 = nqb0 + 2 * HEADS * HD;
  size_t stotal = (size_t)(2 * HEADS * HD * HD + 4 * HEADS * HD) * sizeof(float);
  off += stotal;
  float* wcomb = (float*)(ws + off); off += (size_t)CIN * CIN * sizeof(float);
  off = (off + 255) & ~(size_t)255;
  unsigned short* wfq = (unsigned short*)(ws + off);           // qkv W frags
  off += (size_t)9 * 1536 * 8 * sizeof(unsigned short);        // 221 KB
  unsigned short* wfc = (unsigned short*)(ws + off);           // wcomb frags
  off += (size_t)3 * 1536 * 8 * sizeof(unsigned short);        // 73.7 KB

  hipMemsetAsync(Sb0, 0, stotal, stream);
  k_wfrag<<<54, 256, 0, stream>>>(qkv_w, wfq, 9 * 1536);

  for (int b = 0; b < 2; ++b) {
    const float* xb = x + (size_t)b * CIN * NTOK;
    k_gemm_rr<0, 0><<<NTOK / 64, 256, 0, stream>>>(xb, wfq, qkv_b, pre, 9);
    dim3 g2(4, C3);
    k_dwconv<<<g2, 256, 0, stream>>>(pre, dw_w, dw_b, post);
    float* Sb  = Sb0 + (size_t)b * HEADS * HD * HD;
    float* nqb = nqb0 + (size_t)b * HEADS * HD;
    float* nkb = nkb0 + (size_t)b * HEADS * HD;
    dim3 g3(32, HEADS);
    k_gram<<<g3, 256, 0, stream>>>(post, Sb, nqb, nkb);
    k_attn_wcomb<<<HEADS, 256, 0, stream>>>(Sb, nqb, nkb, temp, proj_w, wcomb);
    k_wfrag<<<18, 256, 0, stream>>>(wcomb, wfc, 3 * 1536);
    k_gemm_rr<1, 1><<<NTOK / 64, 256, 0, stream>>>(post + (size_t)384 * NTOK, wfc,
                                                   proj_b, out + (size_t)b * CIN * NTOK, 3);
  }
}

// Round 8
// 191.972 us; speedup vs baseline: 1.2278x; 1.2100x over previous
//
#include <hip/hip_runtime.h>

#define NTOK 32768   // 8*64*64 tokens
#define CIN 192
#define C3 576
#define HEADS 8
#define HD 24

typedef __attribute__((ext_vector_type(8))) short bf16x8;
typedef __attribute__((ext_vector_type(16))) float f32x16;
typedef __attribute__((ext_vector_type(4))) unsigned int u32x4;

__device__ __forceinline__ float bf2f(unsigned int u) {
  union { unsigned int i; float f; } x; x.i = u << 16; return x.f;
}
__device__ __forceinline__ unsigned short f2bf(float f) {
  union { float f; unsigned int i; } x; x.f = f;
  unsigned int r = x.i + 0x7fffu + ((x.i >> 16) & 1u);
  return (unsigned short)(r >> 16);
}

// ---------------------------------------------------------------------------
// k_wfrag: fp32 W[O][192] -> bf16 MFMA-A-fragment-linear table.
// chunk g = ((otile*12 + kk)*2 + hi)*64 + olane holds W[otile*64+olane][kk*16+hi*8..+7]
// ---------------------------------------------------------------------------
__global__ __launch_bounds__(256) void k_wfrag(const float* __restrict__ W,
                                               unsigned short* __restrict__ Wf,
                                               int nchunk) {
  const int g = blockIdx.x * 256 + threadIdx.x;
  if (g >= nchunk) return;
  const int ol = g & 63, hi = (g >> 6) & 1, kk = (g >> 7) % 12, ot = g / 1536;
  const float* src = W + (size_t)(ot * 64 + ol) * CIN + kk * 16 + hi * 8;
  bf16x8 p;
#pragma unroll
  for (int e = 0; e < 8; ++e) p[e] = (short)f2bf(src[e]);
  *(bf16x8*)&Wf[(size_t)g * 8] = p;
}

// ---------------------------------------------------------------------------
// k_gemm_rr: Y[o,n] = bias[o] + sum_c W[o,c]*X[c,n], K=192 in registers.
// Block = one 64-n tile x one o-chunk (ot_per 64-o tiles).
// grid = 512 * nchunks; oc = bid>>9. X staged to LDS once -> 12 reg B-frags;
// barrier-free o-loop: 12 batched A-frag loads (global, L2) -> 12 MFMA
// (2 chains) -> direct coalesced global stores. No LDS epilogue, 1 barrier.
// ---------------------------------------------------------------------------
template<int XBF, int OUTF32>
__global__ __launch_bounds__(256, 3) void k_gemm_rr(
    const void* __restrict__ Xv, const unsigned short* __restrict__ Wf,
    const float* __restrict__ bias, void* __restrict__ Yv, int ot_per)
{
  __shared__ __align__(16) unsigned short Xl[192][68];   // 26112 B
  const int tid = threadIdx.x;
  const int oc = blockIdx.x >> 9;
  const int n0 = (blockIdx.x & 511) * 64;

  // ---- stage X -> Xl[c][n] (vectorized, coalesced)
  if (XBF) {
    const unsigned short* X = (const unsigned short*)Xv;
#pragma unroll
    for (int i = 0; i < 12; ++i) {
      const int g = tid + i * 256;          // 0..3071
      const int c = g >> 4, nq = (g & 15) * 4;
      *(unsigned long long*)&Xl[c][nq] =
          *(const unsigned long long*)&X[(size_t)c * NTOK + n0 + nq];
    }
  } else {
    const float* X = (const float*)Xv;
#pragma unroll
    for (int i = 0; i < 12; ++i) {
      const int g = tid + i * 256;
      const int c = g >> 4, nq = (g & 15) * 4;
      float4 v = *(const float4*)&X[(size_t)c * NTOK + n0 + nq];
      unsigned short p[4] = {f2bf(v.x), f2bf(v.y), f2bf(v.z), f2bf(v.w)};
      *(unsigned long long*)&Xl[c][nq] = *(unsigned long long*)p;
    }
  }
  __syncthreads();

  const int lane = tid & 63;
  const int wv = tid >> 6;
  const int o_w = (wv >> 1) * 32;
  const int n_w = (wv & 1) * 32;
  const int j = lane & 31;
  const int hi = lane >> 5;

  // ---- repack B-frags to registers (read-only after barrier; no 2nd barrier)
  bf16x8 bfr[12];
#pragma unroll
  for (int kk = 0; kk < 12; ++kk)
#pragma unroll
    for (int e = 0; e < 8; ++e)
      bfr[kk][e] = (short)Xl[kk * 16 + hi * 8 + e][n_w + j];

  // ---- barrier-free o-loop
  for (int it = 0; it < ot_per; ++it) {
    const int ot_idx = oc * ot_per + it;
    const int o0 = ot_idx * 64;
    const unsigned short* wp =
        Wf + ((size_t)ot_idx * 1536 + hi * 64 + o_w + j) * 8;

    bf16x8 a[12];
#pragma unroll
    for (int kk = 0; kk < 12; ++kk)
      a[kk] = *(const bf16x8*)(wp + kk * 1024);

    f32x16 acc0, acc1;
#pragma unroll
    for (int i = 0; i < 16; ++i) { acc0[i] = 0.f; acc1[i] = 0.f; }
#pragma unroll
    for (int kp = 0; kp < 6; ++kp) {
      acc0 = __builtin_amdgcn_mfma_f32_32x32x16_bf16(a[2 * kp], bfr[2 * kp], acc0, 0, 0, 0);
      acc1 = __builtin_amdgcn_mfma_f32_32x32x16_bf16(a[2 * kp + 1], bfr[2 * kp + 1], acc1, 0, 0, 0);
    }

    if (OUTF32) {
      float* Y = (float*)Yv;
#pragma unroll
      for (int r = 0; r < 16; ++r) {
        const int row = o_w + (r & 3) + 8 * (r >> 2) + 4 * hi;
        Y[(size_t)(o0 + row) * NTOK + n0 + n_w + j] =
            acc0[r] + acc1[r] + bias[o0 + row];
      }
    } else {
      unsigned short* Y = (unsigned short*)Yv;
#pragma unroll
      for (int r = 0; r < 16; ++r) {
        const int row = o_w + (r & 3) + 8 * (r >> 2) + 4 * hi;
        Y[(size_t)(o0 + row) * NTOK + n0 + n_w + j] =
            f2bf(acc0[r] + acc1[r] + bias[o0 + row]);
      }
    }
  }
}

// ---------------------------------------------------------------------------
// K2: depthwise 3x3x3, pad 1, bf16 in/out, fp32 math. (unchanged)
// ---------------------------------------------------------------------------
__global__ __launch_bounds__(256, 4) void k_dwconv(
    const unsigned short* __restrict__ in,   // [576][8][64][64] bf16
    const float* __restrict__ wdw,           // [576][27]
    const float* __restrict__ bdw,           // [576]
    unsigned short* __restrict__ out)        // [576][8][64][64] bf16
{
  __shared__ __align__(16) unsigned short s[8][18][76];
  const int tid = threadIdx.x;
  const int ch = blockIdx.y;
  const int h0 = blockIdx.x * 16;
  const unsigned short* inch = in + (size_t)ch * NTOK;

  for (int r = tid; r < 144; r += 256) {
    const int t = r / 18, rr = r % 18;
    s[t][rr][7] = 0;
    s[t][rr][72] = 0;
  }
  for (int idx = tid; idx < 144 * 8; idx += 256) {
    const int row = idx >> 3, seg = idx & 7;
    const int t = row / 18, rr = row % 18;
    const int h = h0 + rr - 1;
    u32x4 v = {0u, 0u, 0u, 0u};
    if (h >= 0 && h < 64)
      v = *(const u32x4*)&inch[t * 4096 + h * 64 + seg * 8];
    *(u32x4*)&s[t][rr][8 + seg * 8] = v;
  }
  float wr[27];
#pragma unroll
  for (int i = 0; i < 27; ++i) wr[i] = wdw[ch * 27 + i];
  const float bias = bdw[ch];
  __syncthreads();

  const int wloc = tid & 63;
  const int hl0 = (tid >> 6) * 4;
  float acc[8][4];
#pragma unroll
  for (int t = 0; t < 8; ++t)
#pragma unroll
    for (int i = 0; i < 4; ++i) acc[t][i] = 0.f;

#pragma unroll
  for (int tt = 0; tt < 8; ++tt) {
    float v[6][3];
#pragma unroll
    for (int r = 0; r < 6; ++r)
#pragma unroll
      for (int c = 0; c < 3; ++c)
        v[r][c] = bf2f(s[tt][hl0 + r][7 + wloc + c]);
#pragma unroll
    for (int p = 0; p < 3; ++p) {
      const int t = tt + 1 - p;
      if (t < 0 || t > 7) continue;
#pragma unroll
      for (int hi = 0; hi < 4; ++hi) {
        float a = 0.f;
#pragma unroll
        for (int dh = 0; dh < 3; ++dh)
#pragma unroll
          for (int dw = 0; dw < 3; ++dw)
            a += wr[p * 9 + dh * 3 + dw] * v[hi + dh][dw];
        acc[t][hi] += a;
      }
    }
  }

  unsigned short* outch = out + (size_t)ch * NTOK;
#pragma unroll
  for (int t = 0; t < 8; ++t)
#pragma unroll
    for (int hi = 0; hi < 4; ++hi)
      outch[t * 4096 + (h0 + hl0 + hi) * 64 + wloc] = f2bf(acc[t][hi] + bias);
}

// ---------------------------------------------------------------------------
// K3: Gram via MFMA, fragments loaded DIRECTLY from global. (unchanged)
// ---------------------------------------------------------------------------
__global__ __launch_bounds__(256) void k_gram(
    const unsigned short* __restrict__ post,
    float* __restrict__ Sb, float* __restrict__ nqb, float* __restrict__ nkb)
{
  const int tid = threadIdx.x;
  const int h = blockIdx.y;
  const int lane = tid & 63;
  const int wv = tid >> 6;
  const int c = lane & 31;
  const int off = (lane >> 5) * 8;
  const unsigned short* q = post + (size_t)(h * HD + c) * NTOK;
  const unsigned short* k = post + (size_t)(192 + h * HD + c) * NTOK;

  __shared__ float Sl[24][25];
  __shared__ float nl[48];
  for (int i = tid; i < 600; i += 256) ((float*)Sl)[i] = 0.f;
  if (tid < 48) nl[tid] = 0.f;
  __syncthreads();

  f32x16 acc;
#pragma unroll
  for (int i = 0; i < 16; ++i) acc[i] = 0.f;
  float sqq = 0.f, sqk = 0.f;

  const int base = blockIdx.x * 1024 + wv * 256 + off;
#pragma unroll
  for (int i = 0; i < 16; ++i) {
    const int n = base + i * 16;
    bf16x8 a = *(const bf16x8*)&q[n];
    bf16x8 b = *(const bf16x8*)&k[n];
#pragma unroll
    for (int e = 0; e < 8; ++e) {
      float fa = bf2f((unsigned short)a[e]);
      float fb = bf2f((unsigned short)b[e]);
      sqq += fa * fa;
      sqk += fb * fb;
    }
    acc = __builtin_amdgcn_mfma_f32_32x32x16_bf16(a, b, acc, 0, 0, 0);
  }

  sqq += __shfl_down(sqq, 32, 64);
  sqk += __shfl_down(sqk, 32, 64);
  if (lane < 32 && c < 24) {
    atomicAdd(&nl[c], sqq);
    atomicAdd(&nl[24 + c], sqk);
  }
  if (c < 24) {
#pragma unroll
    for (int r = 0; r < 16; ++r) {
      const int row = (r & 3) + 8 * (r >> 2) + 4 * (lane >> 5);
      if (row < 24) atomicAdd(&Sl[row][c], acc[r]);
    }
  }
  __syncthreads();
  for (int i = tid; i < 576; i += 256)
    atomicAdd(&Sb[h * 576 + i], Sl[i / 24][i % 24]);
  if (tid < 24) atomicAdd(&nqb[h * 24 + tid], nl[tid]);
  else if (tid < 48) atomicAdd(&nkb[h * 24 + tid - 24], nl[tid]);
}

// ---------------------------------------------------------------------------
// K4: attn = softmax(S*temp/(|q||k|)); Wcomb = projW @ attn (per head)
// ---------------------------------------------------------------------------
__global__ __launch_bounds__(256) void k_attn_wcomb(
    const float* __restrict__ Sb, const float* __restrict__ nqb,
    const float* __restrict__ nkb, const float* __restrict__ temp,
    const float* __restrict__ projw, float* __restrict__ wcomb)
{
  const int h = blockIdx.x;
  const int tid = threadIdx.x;
  __shared__ float attn[24][25];
  __shared__ float nqs[24], nks[24];
  if (tid < 24) nqs[tid] = fmaxf(sqrtf(nqb[h * 24 + tid]), 1e-12f);
  else if (tid < 48) nks[tid - 24] = fmaxf(sqrtf(nkb[h * 24 + tid - 24]), 1e-12f);
  __syncthreads();
  if (tid < 24) {
    const int c = tid;
    const float tmp = temp[h];
    float row[24];
    float m = -1e30f;
#pragma unroll
    for (int d = 0; d < 24; ++d) {
      float v = Sb[h * 576 + c * 24 + d] / (nqs[c] * nks[d]) * tmp;
      row[d] = v;
      m = fmaxf(m, v);
    }
    float ssum = 0.f;
#pragma unroll
    for (int d = 0; d < 24; ++d) { float e = __expf(row[d] - m); row[d] = e; ssum += e; }
    const float inv = 1.f / ssum;
#pragma unroll
    for (int d = 0; d < 24; ++d) attn[c][d] = row[d] * inv;
  }
  __syncthreads();
  for (int e = tid; e < 192 * 24; e += 256) {
    int o = e / 24, d = e % 24;
    float a = 0.f;
#pragma unroll
    for (int c = 0; c < 24; ++c) a += projw[o * 192 + h * 24 + c] * attn[c][d];
    wcomb[o * 192 + h * 24 + d] = a;
  }
}

// ---------------------------------------------------------------------------
extern "C" void kernel_launch(void* const* d_in, const int* in_sizes, int n_in,
                              void* d_out, int out_size, void* d_ws, size_t ws_size,
                              hipStream_t stream) {
  const float* x      = (const float*)d_in[0];
  const float* qkv_w  = (const float*)d_in[1];
  const float* qkv_b  = (const float*)d_in[2];
  const float* dw_w   = (const float*)d_in[3];
  const float* dw_b   = (const float*)d_in[4];
  const float* temp   = (const float*)d_in[5];
  const float* proj_w = (const float*)d_in[6];
  const float* proj_b = (const float*)d_in[7];
  float* out = (float*)d_out;

  char* ws = (char*)d_ws;
  size_t off = 0;
  unsigned short* post = (unsigned short*)(ws + off);
  off += (size_t)C3 * NTOK * sizeof(unsigned short);           // 37.75 MB
  unsigned short* pre = (unsigned short*)(ws + off);
  off += (size_t)C3 * NTOK * sizeof(unsigned short);           // 37.75 MB
  float* Sb0  = (float*)(ws + off);
  float* nqb0 = Sb0 + 2 * HEADS * HD * HD;
  float* nkb0 = nqb0 + 2 * HEADS * HD;
  size_t stotal = (size_t)(2 * HEADS * HD * HD + 4 * HEADS * HD) * sizeof(float);
  off += stotal;
  float* wcomb = (float*)(ws + off); off += (size_t)CIN * CIN * sizeof(float);
  off = (off + 255) & ~(size_t)255;
  unsigned short* wfq = (unsigned short*)(ws + off);           // qkv W frags
  off += (size_t)9 * 1536 * 8 * sizeof(unsigned short);        // 221 KB
  unsigned short* wfc = (unsigned short*)(ws + off);           // wcomb frags
  off += (size_t)3 * 1536 * 8 * sizeof(unsigned short);        // 73.7 KB

  hipMemsetAsync(Sb0, 0, stotal, stream);
  k_wfrag<<<54, 256, 0, stream>>>(qkv_w, wfq, 9 * 1536);

  for (int b = 0; b < 2; ++b) {
    const float* xb = x + (size_t)b * CIN * NTOK;
    k_gemm_rr<0, 0><<<1536, 256, 0, stream>>>(xb, wfq, qkv_b, pre, 3);
    dim3 g2(4, C3);
    k_dwconv<<<g2, 256, 0, stream>>>(pre, dw_w, dw_b, post);
    float* Sb  = Sb0 + (size_t)b * HEADS * HD * HD;
    float* nqb = nqb0 + (size_t)b * HEADS * HD;
    float* nkb = nkb0 + (size_t)b * HEADS * HD;
    dim3 g3(32, HEADS);
    k_gram<<<g3, 256, 0, stream>>>(post, Sb, nqb, nkb);
    k_attn_wcomb<<<HEADS, 256, 0, stream>>>(Sb, nqb, nkb, temp, proj_w, wcomb);
    k_wfrag<<<18, 256, 0, stream>>>(wcomb, wfc, 3 * 1536);
    k_gemm_rr<1, 1><<<512, 256, 0, stream>>>(post + (size_t)384 * NTOK, wfc,
                                             proj_b, out + (size_t)b * CIN * NTOK, 3);
  }
}